// Round 2
// baseline (656.392 us; speedup 1.0000x reference)
//
#include <hip/hip_runtime.h>
#include <hip/hip_bf16.h>

#define DIM 2048
#define NHEADS 16
#define HEAD_DIM 128
#define HIDDEN 2048
#define SEQ 4096
#define BATCH 2
#define BT (BATCH * SEQ)        // 8192
#define NSEG 64
#define SEGLEN (SEQ / NSEG)     // 64
#define N_GATE (3 * HIDDEN)     // 6144

typedef __bf16 bf16_t;
typedef __bf16 bf16x8 __attribute__((ext_vector_type(8)));
typedef __bf16 bf16x4_t __attribute__((ext_vector_type(4)));
typedef float f32x4 __attribute__((ext_vector_type(4)));

__device__ __forceinline__ void gload_lds16(const void* g, void* l) {
  __builtin_amdgcn_global_load_lds(
      (const __attribute__((address_space(1))) void*)g,
      (__attribute__((address_space(3))) void*)l, 16, 0, 0);
}

// ---------------- prep: f32 -> bf16 convert (vectorized) ----------------
__global__ void cvt_f32_bf16(const float* __restrict__ src, bf16_t* __restrict__ dst, int n4) {
  int i = blockIdx.x * blockDim.x + threadIdx.x;
  if (i >= n4) return;
  float4 v = reinterpret_cast<const float4*>(src)[i];
  bf16x4_t o;
  o[0] = (bf16_t)v.x; o[1] = (bf16_t)v.y; o[2] = (bf16_t)v.z; o[3] = (bf16_t)v.w;
  reinterpret_cast<bf16x4_t*>(dst)[i] = o;
}

// ---------------- f gate in pure fp32 (precision-critical) ----------------
__global__ void fgate_kernel(const float* __restrict__ x, const float* __restrict__ Wg,
                             const float* __restrict__ bg, float* __restrict__ fout) {
  int idx = blockIdx.x * 256 + threadIdx.x;
  int bt = idx >> 4, h = idx & 15;
  const float* xr = x + (size_t)bt * DIM;
  const float* wr = Wg + (size_t)h * DIM;
  float acc = 0.f;
  for (int k = 0; k < DIM; k += 4) {
    float4 xv = *reinterpret_cast<const float4*>(xr + k);
    float4 wv = *reinterpret_cast<const float4*>(wr + k);
    acc = fmaf(xv.x, wv.x, acc);
    acc = fmaf(xv.y, wv.y, acc);
    acc = fmaf(xv.z, wv.z, acc);
    acc = fmaf(xv.w, wv.w, acc);
  }
  acc += bg[h];
  fout[idx] = 1.f / (1.f + expf(-acc));
}

// ---------------- 256x256 tile, BK=32, 4-deep LDS ring, counted-vmcnt GEMM ----
// A (MxK) row-major, B (NxK) row-major (i.e. C = A * B^T), K = 2048.
// LDS swizzle: within each 64B row, 16B-chunk index c4 stored at c4 ^ (row&3).
// global_load_lds writes linearly (wave-uniform base + lane*16B), so the
// swizzle is applied by pre-swizzling the per-lane GLOBAL source address
// (rule 21), and un-applied on the ds_read side.
// MODE 0: gates GEMM -> sigmoid/tanh/copy into Oi/Ot/Oo (bf16).
// MODE 1: output GEMM -> +bias, fp32 to Of.

__device__ __forceinline__ void stage_one(const bf16_t* __restrict__ G, bf16_t* lds_op,
                                          int grow0, int k0, int j, int wid, int lane) {
  // one global_load_lds_dwordx4 per lane; covers 8KB (128 rows x 64B) per call
  const int chunk = j * 512 + wid * 64 + lane;   // 16B chunk id within 256x32 tile
  const int row = chunk >> 2;                    // 0..255
  const int c4s = chunk & 3;                     // stored chunk slot
  const int c4d = c4s ^ (row & 3);               // which data chunk lives here
  const bf16_t* src = G + (size_t)(grow0 + row) * 2048 + k0 + c4d * 8;
  bf16_t* dst = lds_op + (j * 512 + wid * 64) * 8;  // wave-uniform base
  gload_lds16(src, dst);
}

template <int MODE>
__global__ __launch_bounds__(512, 1)
void gemm256(const bf16_t* __restrict__ A, const bf16_t* __restrict__ B,
             const float* __restrict__ bias,
             bf16_t* __restrict__ Oi, bf16_t* __restrict__ Ot, bf16_t* __restrict__ Oo,
             float* __restrict__ Of, int tiles_n) {
  __shared__ __align__(16) bf16_t As[4][256 * 32];
  __shared__ __align__(16) bf16_t Bs[4][256 * 32];
  constexpr int KT = 64;  // 2048 / 32

  const int tid = threadIdx.x;
  const int wid = tid >> 6, lane = tid & 63;
  const int nwg = gridDim.x;
  const int bid = blockIdx.x;
  // T1: bijective XCD swizzle (nwg % 8 == 0 for both call sites)
  const int swz = (bid & 7) * (nwg >> 3) + (bid >> 3);
  const int tm = swz / tiles_n;
  const int tn = swz - tm * tiles_n;
  const int brow = tm * 256, bcol = tn * 256;
  const int wm = wid >> 2, wn = wid & 3;  // 2M x 4N waves; wave output 128x64

  f32x4 acc[8][4] = {};

  // prologue: stage tiles 0,1,2 (12 loads/wave in flight)
#pragma unroll
  for (int t = 0; t < 3; ++t) {
#pragma unroll
    for (int j = 0; j < 2; ++j) {
      stage_one(A, As[t], brow, t * 32, j, wid, lane);
      stage_one(B, Bs[t], bcol, t * 32, j, wid, lane);
    }
  }

  for (int kt = 0; kt < KT; ++kt) {
    // counted vmcnt: drain tile kt, keep kt+1/kt+2 (8 loads) in flight
    if (kt < KT - 2)       asm volatile("s_waitcnt vmcnt(8)" ::: "memory");
    else if (kt == KT - 2) asm volatile("s_waitcnt vmcnt(4)" ::: "memory");
    else                   asm volatile("s_waitcnt vmcnt(0)" ::: "memory");
    __builtin_amdgcn_s_barrier();
    asm volatile("" ::: "memory");

    const int s = kt & 3;
    const bf16_t* as = As[s];
    const bf16_t* bs = Bs[s];
    const bool do_stage = (kt + 3) < KT;
    const int s3 = (kt + 3) & 3;
    const int k03 = (kt + 3) * 32;

    bf16x8 bfr[4];
#pragma unroll
    for (int ni = 0; ni < 4; ++ni) {
      int r = wn * 64 + ni * 16 + (lane & 15);
      bfr[ni] = *reinterpret_cast<const bf16x8*>(&bs[r * 32 + (((lane >> 4) ^ (r & 3))) * 8]);
    }

#pragma unroll
    for (int q = 0; q < 4; ++q) {
      // T3: issue one stage load of tile kt+3 per sub-phase (slot freed at kt-1)
      if (do_stage) {
        if (q < 2) stage_one(A, As[s3], brow, k03, q, wid, lane);
        else       stage_one(B, Bs[s3], bcol, k03, q - 2, wid, lane);
      }
      int r0 = wm * 128 + (2 * q) * 16 + (lane & 15);
      int r1 = r0 + 16;
      bf16x8 af0 = *reinterpret_cast<const bf16x8*>(&as[r0 * 32 + (((lane >> 4) ^ (r0 & 3))) * 8]);
      bf16x8 af1 = *reinterpret_cast<const bf16x8*>(&as[r1 * 32 + (((lane >> 4) ^ (r1 & 3))) * 8]);
      __builtin_amdgcn_s_setprio(1);
#pragma unroll
      for (int ni = 0; ni < 4; ++ni) {
        acc[2 * q][ni]     = __builtin_amdgcn_mfma_f32_16x16x32_bf16(af0, bfr[ni], acc[2 * q][ni], 0, 0, 0);
        acc[2 * q + 1][ni] = __builtin_amdgcn_mfma_f32_16x16x32_bf16(af1, bfr[ni], acc[2 * q + 1][ni], 0, 0, 0);
      }
      __builtin_amdgcn_s_setprio(0);
    }
    asm volatile("" ::: "memory");
    __builtin_amdgcn_s_barrier();
    asm volatile("" ::: "memory");
  }

  // epilogue. C/D layout: col = lane&15, row = (lane>>4)*4 + q  [m89/m91]
  const int crow0 = brow + wm * 128;
  const int ccol0 = bcol + wn * 64;
  if (MODE == 0) {
    const int section = bcol >> 11;  // 256-tile lies fully inside one 2048-section
    bf16_t* dst = (section == 0) ? Oi : ((section == 1) ? Ot : Oo);
#pragma unroll
    for (int mi = 0; mi < 8; ++mi)
#pragma unroll
      for (int ni = 0; ni < 4; ++ni) {
        int gcol = ccol0 + ni * 16 + (lane & 15);
        int col = gcol & 2047;
        float b = bias[gcol];
#pragma unroll
        for (int q = 0; q < 4; ++q) {
          int row = crow0 + mi * 16 + (lane >> 4) * 4 + q;
          float v = acc[mi][ni][q] + b;
          float a;
          if (section == 0)      a = 1.f / (1.f + __expf(-v));
          else if (section == 1) a = tanhf(v);
          else                   a = v;
          dst[(size_t)row * HIDDEN + col] = (bf16_t)a;
        }
      }
  } else {
#pragma unroll
    for (int mi = 0; mi < 8; ++mi)
#pragma unroll
      for (int ni = 0; ni < 4; ++ni) {
        int col = ccol0 + ni * 16 + (lane & 15);
        float b = bias[col];
#pragma unroll
        for (int q = 0; q < 4; ++q) {
          int row = crow0 + mi * 16 + (lane >> 4) * 4 + q;
          Of[(size_t)row * DIM + col] = acc[mi][ni][q] + b;
        }
      }
  }
}

// ---------------- segmented scan ----------------
__global__ void scan_pass1(const float* __restrict__ fg, const bf16_t* __restrict__ gi,
                           const bf16_t* __restrict__ gt, float* __restrict__ cend,
                           float* __restrict__ pseg) {
  int bx = blockIdx.x;
  int chblk = bx & 7, seg = (bx >> 3) & 63, b = bx >> 9;
  int ch = chblk * 256 + threadIdx.x;
  int head = ch >> 7;
  float c = 0.f, P = 1.f;
  size_t t0 = (size_t)b * SEQ + (size_t)seg * SEGLEN;
  for (int tt = 0; tt < SEGLEN; ++tt) {
    size_t bt = t0 + tt;
    float f = fg[bt * NHEADS + head];
    float iv = (float)gi[bt * HIDDEN + ch];
    float tv = (float)gt[bt * HIDDEN + ch];
    c = fmaf(f, c, iv * tv);
    P *= f;
  }
  size_t o = ((size_t)b * NSEG + seg) * HIDDEN + ch;
  cend[o] = c;
  pseg[o] = P;
}

__global__ void scan_pass2(const float* __restrict__ cend, const float* __restrict__ pseg,
                           float* __restrict__ cin) {
  int idx = blockIdx.x * 256 + threadIdx.x;  // 4096
  int b = idx >> 11, ch = idx & 2047;
  float C = 0.f;
  for (int s = 0; s < NSEG; ++s) {
    size_t o = ((size_t)b * NSEG + s) * HIDDEN + ch;
    cin[o] = C;
    C = cend[o] + pseg[o] * C;
  }
}

__global__ void scan_pass3(const float* __restrict__ fg, const bf16_t* __restrict__ gi,
                           const bf16_t* __restrict__ gt, const bf16_t* __restrict__ go,
                           const float* __restrict__ cin, bf16_t* __restrict__ h) {
  int bx = blockIdx.x;
  int chblk = bx & 7, seg = (bx >> 3) & 63, b = bx >> 9;
  int ch = chblk * 256 + threadIdx.x;
  int head = ch >> 7;
  float c = cin[((size_t)b * NSEG + seg) * HIDDEN + ch];
  size_t t0 = (size_t)b * SEQ + (size_t)seg * SEGLEN;
  for (int tt = 0; tt < SEGLEN; ++tt) {
    size_t bt = t0 + tt;
    float f = fg[bt * NHEADS + head];
    float iv = (float)gi[bt * HIDDEN + ch];
    float tv = (float)gt[bt * HIDDEN + ch];
    c = fmaf(f, c, iv * tv);
    float hv = (float)go[bt * HIDDEN + ch] * tanhf(c);
    h[bt * HIDDEN + ch] = (bf16_t)hv;
  }
}

extern "C" void kernel_launch(void* const* d_in, const int* in_sizes, int n_in,
                              void* d_out, int out_size, void* d_ws, size_t ws_size,
                              hipStream_t stream) {
  const float* x  = (const float*)d_in[0];
  const float* Wg = (const float*)d_in[1];
  const float* bg = (const float*)d_in[2];
  const float* Wo = (const float*)d_in[3];
  const float* bo = (const float*)d_in[4];
  float* out = (float*)d_out;

  char* ws = (char*)d_ws;
  size_t off = 0;
  auto alloc = [&](size_t bytes) -> void* {
    void* p = ws + off;
    off += (bytes + 255) & ~(size_t)255;
    return p;
  };
  bf16_t* xb   = (bf16_t*)alloc((size_t)BT * DIM * 2);
  bf16_t* wgb  = (bf16_t*)alloc((size_t)N_GATE * DIM * 2);
  bf16_t* wob  = (bf16_t*)alloc((size_t)DIM * HIDDEN * 2);
  float*  fg   = (float*)alloc((size_t)BT * NHEADS * 4);
  bf16_t* gi   = (bf16_t*)alloc((size_t)BT * HIDDEN * 2);
  bf16_t* gt   = (bf16_t*)alloc((size_t)BT * HIDDEN * 2);
  bf16_t* go   = (bf16_t*)alloc((size_t)BT * HIDDEN * 2);
  bf16_t* hbuf = (bf16_t*)alloc((size_t)BT * HIDDEN * 2);
  float*  cend = (float*)alloc((size_t)BATCH * NSEG * HIDDEN * 4);
  float*  pseg = (float*)alloc((size_t)BATCH * NSEG * HIDDEN * 4);
  float*  cin  = (float*)alloc((size_t)BATCH * NSEG * HIDDEN * 4);
  (void)ws_size; (void)in_sizes; (void)n_in; (void)out_size;

  // prep converts
  {
    int n4 = BT * DIM / 4;
    cvt_f32_bf16<<<(n4 + 255) / 256, 256, 0, stream>>>(x, xb, n4);
  }
  {
    int n4 = N_GATE * DIM / 4;
    cvt_f32_bf16<<<(n4 + 255) / 256, 256, 0, stream>>>(Wg + (size_t)NHEADS * DIM, wgb, n4);
  }
  {
    int n4 = DIM * HIDDEN / 4;
    cvt_f32_bf16<<<(n4 + 255) / 256, 256, 0, stream>>>(Wo, wob, n4);
  }

  // f gate in fp32
  fgate_kernel<<<(BT * NHEADS) / 256, 256, 0, stream>>>(x, Wg, bg, fg);

  // gates GEMM: M=8192, N=6144, K=2048 -> 32x24 = 768 tiles
  gemm256<0><<<768, 512, 0, stream>>>(xb, wgb, bg + NHEADS, gi, gt, go, nullptr, 24);

  // segmented scan
  scan_pass1<<<BATCH * NSEG * (HIDDEN / 256), 256, 0, stream>>>(fg, gi, gt, cend, pseg);
  scan_pass2<<<BATCH * HIDDEN / 256, 256, 0, stream>>>(cend, pseg, cin);
  scan_pass3<<<BATCH * NSEG * (HIDDEN / 256), 256, 0, stream>>>(fg, gi, gt, go, cin, hbuf);

  // output GEMM: M=8192, N=2048, K=2048 -> 32x8 = 256 tiles
  gemm256<1><<<256, 512, 0, stream>>>(hbuf, wob, bo, nullptr, nullptr, nullptr, out, 8);
}

// Round 4
// 599.257 us; speedup vs baseline: 1.0953x; 1.0953x over previous
//
#include <hip/hip_runtime.h>
#include <hip/hip_bf16.h>

#define DIM 2048
#define NHEADS 16
#define HEAD_DIM 128
#define HIDDEN 2048
#define SEQ 4096
#define BATCH 2
#define BT (BATCH * SEQ)        // 8192
#define NSEG 64
#define SEGLEN (SEQ / NSEG)     // 64
#define N_GATE (3 * HIDDEN)     // 6144

typedef __bf16 bf16_t;
typedef __bf16 bf16x8 __attribute__((ext_vector_type(8)));
typedef __bf16 bf16x4_t __attribute__((ext_vector_type(4)));
typedef float f32x4 __attribute__((ext_vector_type(4)));

__device__ __forceinline__ void gload_lds16(const void* g, void* l) {
  __builtin_amdgcn_global_load_lds(
      (const __attribute__((address_space(1))) void*)g,
      (__attribute__((address_space(3))) void*)l, 16, 0, 0);
}

#define MEMFENCE asm volatile("" ::: "memory")
#define BAR do { MEMFENCE; __builtin_amdgcn_s_barrier(); MEMFENCE; } while (0)
#define LGKM0 do { asm volatile("s_waitcnt lgkmcnt(0)" ::: "memory"); \
                   __builtin_amdgcn_sched_barrier(0); } while (0)
#define VMCNT(n) asm volatile("s_waitcnt vmcnt(" #n ")" ::: "memory")

// ---------------- prep: f32 -> bf16 convert (vectorized) ----------------
__global__ void cvt_f32_bf16(const float* __restrict__ src, bf16_t* __restrict__ dst, int n4) {
  int i = blockIdx.x * blockDim.x + threadIdx.x;
  if (i >= n4) return;
  float4 v = reinterpret_cast<const float4*>(src)[i];
  bf16x4_t o;
  o[0] = (bf16_t)v.x; o[1] = (bf16_t)v.y; o[2] = (bf16_t)v.z; o[3] = (bf16_t)v.w;
  reinterpret_cast<bf16x4_t*>(dst)[i] = o;
}

// ---------------- f gate in pure fp32 (precision-critical) ----------------
__global__ void fgate_kernel(const float* __restrict__ x, const float* __restrict__ Wg,
                             const float* __restrict__ bg, float* __restrict__ fout) {
  int idx = blockIdx.x * 256 + threadIdx.x;
  int bt = idx >> 4, h = idx & 15;
  const float* xr = x + (size_t)bt * DIM;
  const float* wr = Wg + (size_t)h * DIM;
  float acc = 0.f;
  for (int k = 0; k < DIM; k += 4) {
    float4 xv = *reinterpret_cast<const float4*>(xr + k);
    float4 wv = *reinterpret_cast<const float4*>(wr + k);
    acc = fmaf(xv.x, wv.x, acc);
    acc = fmaf(xv.y, wv.y, acc);
    acc = fmaf(xv.z, wv.z, acc);
    acc = fmaf(xv.w, wv.w, acc);
  }
  acc += bg[h];
  fout[idx] = 1.f / (1.f + expf(-acc));
}

// ---------------- 256x256 tile, BK=64, 2-slot dbuf, 4-subphase pipelined GEMM ----
// C = A * B^T, A (MxK) row-major, B (NxK) row-major, K = 2048 (KT = 32 tiles).
// LDS regions: [slot][kh][256 rows][32 cols], 64B rows, chunk swizzle c ^= row&3
// (bank-balanced: 8 distinct addrs per bank per wave b128 read = the 1KB floor).
// global_load_lds writes linearly, so the swizzle is applied by pre-swizzling the
// per-lane GLOBAL source (rule 21) and un-applied on the ds_read address.
// Per K-tile: sp0 (Mhalf0 x Kh0), sp1 (Mhalf1 x Kh0), sp2 (Mhalf0 x Kh1),
// sp3 (Mhalf1 x Kh1); 16 MFMA each. Stages: sp0 -> A-Kh1(t+1), sp1 -> B-Kh1(t+1),
// sp2 -> A-Kh0(t+2), sp3 -> B-Kh0(t+2); each staged region's last reader drained
// (LGKM0) >=2 barriers before the overwriting load is issued. vmcnt(8) at end of
// sp1/sp3 confirms exactly the regions the next phases read; tail 8->4->0.

__device__ __forceinline__ void stage_unit(const bf16_t* __restrict__ G, int grow0, int gcol,
                                           bf16_t* region, int rh, int wid, int lane) {
  const int r = rh * 128 + wid * 16 + (lane >> 2);          // row within 256-row region
  const int c = (lane & 3) ^ ((lane >> 2) & 3);             // logical chunk for this slot
  gload_lds16(G + (size_t)(grow0 + r) * 2048 + gcol + c * 8,
              region + (rh * 128 + wid * 16) * 32);         // wave-uniform linear dst
}

template <int MODE>
__global__ __launch_bounds__(512, 1)
void gemm256(const bf16_t* __restrict__ A, const bf16_t* __restrict__ B,
             const float* __restrict__ bias,
             bf16_t* __restrict__ Oi, bf16_t* __restrict__ Ot, bf16_t* __restrict__ Oo,
             float* __restrict__ Of, int tiles_n) {
  __shared__ __align__(16) bf16_t As[2][2][256 * 32];
  __shared__ __align__(16) bf16_t Bs[2][2][256 * 32];
  constexpr int KT = 32;  // 2048 / 64

  const int tid = threadIdx.x;
  const int wid = tid >> 6, lane = tid & 63;
  const int nwg = gridDim.x, bid = blockIdx.x;
  const int swz = (bid & 7) * (nwg >> 3) + (bid >> 3);      // bijective (nwg%8==0)
  const int tm = swz / tiles_n, tn = swz - tm * tiles_n;
  const int brow = tm * 256, bcol = tn * 256;
  const int wm = wid >> 2, wn = wid & 3;                     // 2M x 4N; wave out 128x64
  const int rl = lane & 15, q = lane >> 4;
  const int fo = (q ^ (rl & 3)) << 3;                        // swizzled chunk elem offset
  const int arow0 = wm * 128 + rl;
  const int brow0 = wn * 64 + rl;   // FIXED: was (wn&1)*64 -- must match ccol0 = wn*64

  f32x4 acc[8][4] = {};

#define FRAG(regptr, row) (*reinterpret_cast<const bf16x8*>(&(regptr)[(row) * 32 + fo]))

  // prologue: tile0 Kh0+Kh1, tile1 Kh0 (12 loads/thread; vmcnt(8) confirms tile0 Kh0)
#pragma unroll
  for (int rh = 0; rh < 2; ++rh) stage_unit(A, brow, 0,      &As[0][0][0], rh, wid, lane);
#pragma unroll
  for (int rh = 0; rh < 2; ++rh) stage_unit(B, bcol, 0,      &Bs[0][0][0], rh, wid, lane);
#pragma unroll
  for (int rh = 0; rh < 2; ++rh) stage_unit(A, brow, 32,     &As[0][1][0], rh, wid, lane);
#pragma unroll
  for (int rh = 0; rh < 2; ++rh) stage_unit(B, bcol, 32,     &Bs[0][1][0], rh, wid, lane);
#pragma unroll
  for (int rh = 0; rh < 2; ++rh) stage_unit(A, brow, 64,     &As[1][0][0], rh, wid, lane);
#pragma unroll
  for (int rh = 0; rh < 2; ++rh) stage_unit(B, bcol, 64,     &Bs[1][0][0], rh, wid, lane);
  VMCNT(8);
  BAR;

  for (int t = 0; t < KT; ++t) {
    const int slot = t & 1, nslot = slot ^ 1;
    const bool s1 = (t + 1) < KT, s2 = (t + 2) < KT;
    const int kc1 = (t + 1) * 64, kc2 = (t + 2) * 64;
    const bf16_t* a0 = &As[slot][0][0];
    const bf16_t* a1 = &As[slot][1][0];
    const bf16_t* b0 = &Bs[slot][0][0];
    const bf16_t* b1 = &Bs[slot][1][0];
    bf16x8 bf[4], af[4];

    // ---- sp0: Mhalf0 x Kh0 ----
#pragma unroll
    for (int ni = 0; ni < 4; ++ni) bf[ni] = FRAG(b0, brow0 + ni * 16);
#pragma unroll
    for (int mi = 0; mi < 4; ++mi) af[mi] = FRAG(a0, arow0 + mi * 16);
    if (s1) { stage_unit(A, brow, kc1 + 32, &As[nslot][1][0], 0, wid, lane);
              stage_unit(A, brow, kc1 + 32, &As[nslot][1][0], 1, wid, lane); }
    BAR; LGKM0;
    __builtin_amdgcn_s_setprio(1);
#pragma unroll
    for (int mi = 0; mi < 4; ++mi)
#pragma unroll
      for (int ni = 0; ni < 4; ++ni)
        acc[mi][ni] = __builtin_amdgcn_mfma_f32_16x16x32_bf16(af[mi], bf[ni], acc[mi][ni], 0, 0, 0);
    __builtin_amdgcn_s_setprio(0);
    BAR;

    // ---- sp1: Mhalf1 x Kh0 (reuse bf) ----
#pragma unroll
    for (int mi = 0; mi < 4; ++mi) af[mi] = FRAG(a0, arow0 + 64 + mi * 16);
    if (s1) { stage_unit(B, bcol, kc1 + 32, &Bs[nslot][1][0], 0, wid, lane);
              stage_unit(B, bcol, kc1 + 32, &Bs[nslot][1][0], 1, wid, lane); }
    BAR; LGKM0;
    __builtin_amdgcn_s_setprio(1);
#pragma unroll
    for (int mi = 0; mi < 4; ++mi)
#pragma unroll
      for (int ni = 0; ni < 4; ++ni)
        acc[4 + mi][ni] = __builtin_amdgcn_mfma_f32_16x16x32_bf16(af[mi], bf[ni], acc[4 + mi][ni], 0, 0, 0);
    __builtin_amdgcn_s_setprio(0);
    if (t < KT - 1) { VMCNT(8); } else { VMCNT(0); }   // confirm Kh1(t)
    BAR;

    // ---- sp2: Mhalf0 x Kh1 ----
#pragma unroll
    for (int ni = 0; ni < 4; ++ni) bf[ni] = FRAG(b1, brow0 + ni * 16);
#pragma unroll
    for (int mi = 0; mi < 4; ++mi) af[mi] = FRAG(a1, arow0 + mi * 16);
    if (s2) { stage_unit(A, brow, kc2, &As[slot][0][0], 0, wid, lane);
              stage_unit(A, brow, kc2, &As[slot][0][0], 1, wid, lane); }
    BAR; LGKM0;
    __builtin_amdgcn_s_setprio(1);
#pragma unroll
    for (int mi = 0; mi < 4; ++mi)
#pragma unroll
      for (int ni = 0; ni < 4; ++ni)
        acc[mi][ni] = __builtin_amdgcn_mfma_f32_16x16x32_bf16(af[mi], bf[ni], acc[mi][ni], 0, 0, 0);
    __builtin_amdgcn_s_setprio(0);
    BAR;

    // ---- sp3: Mhalf1 x Kh1 (reuse bf) ----
#pragma unroll
    for (int mi = 0; mi < 4; ++mi) af[mi] = FRAG(a1, arow0 + 64 + mi * 16);
    if (s2) { stage_unit(B, bcol, kc2, &Bs[slot][0][0], 0, wid, lane);
              stage_unit(B, bcol, kc2, &Bs[slot][0][0], 1, wid, lane); }
    BAR; LGKM0;
    __builtin_amdgcn_s_setprio(1);
#pragma unroll
    for (int mi = 0; mi < 4; ++mi)
#pragma unroll
      for (int ni = 0; ni < 4; ++ni)
        acc[4 + mi][ni] = __builtin_amdgcn_mfma_f32_16x16x32_bf16(af[mi], bf[ni], acc[4 + mi][ni], 0, 0, 0);
    __builtin_amdgcn_s_setprio(0);
    if (t < KT - 2) { VMCNT(8); } else if (t == KT - 2) { VMCNT(4); } else { VMCNT(0); }
    BAR;
  }
#undef FRAG

  // epilogue. C/D layout: col = lane&15, row = (lane>>4)*4 + q  [m89/m91]
  const int crow0 = brow + wm * 128;
  const int ccol0 = bcol + wn * 64;
  if (MODE == 0) {
    const int section = bcol >> 11;  // 256-tile lies fully inside one 2048-section
    bf16_t* dst = (section == 0) ? Oi : ((section == 1) ? Ot : Oo);
#pragma unroll
    for (int mi = 0; mi < 8; ++mi)
#pragma unroll
      for (int ni = 0; ni < 4; ++ni) {
        int gcol = ccol0 + ni * 16 + (lane & 15);
        int col = gcol & 2047;
        float b = bias[gcol];
#pragma unroll
        for (int qq = 0; qq < 4; ++qq) {
          int row = crow0 + mi * 16 + (lane >> 4) * 4 + qq;
          float v = acc[mi][ni][qq] + b;
          float a;
          if (section == 0)      a = 1.f / (1.f + __expf(-v));
          else if (section == 1) a = tanhf(v);
          else                   a = v;
          dst[(size_t)row * HIDDEN + col] = (bf16_t)a;
        }
      }
  } else {
#pragma unroll
    for (int mi = 0; mi < 8; ++mi)
#pragma unroll
      for (int ni = 0; ni < 4; ++ni) {
        int col = ccol0 + ni * 16 + (lane & 15);
        float b = bias[col];
#pragma unroll
        for (int qq = 0; qq < 4; ++qq) {
          int row = crow0 + mi * 16 + (lane >> 4) * 4 + qq;
          Of[(size_t)row * DIM + col] = acc[mi][ni][qq] + b;
        }
      }
  }
}

// ---------------- segmented scan ----------------
__global__ void scan_pass1(const float* __restrict__ fg, const bf16_t* __restrict__ gi,
                           const bf16_t* __restrict__ gt, float* __restrict__ cend,
                           float* __restrict__ pseg) {
  int bx = blockIdx.x;
  int chblk = bx & 7, seg = (bx >> 3) & 63, b = bx >> 9;
  int ch = chblk * 256 + threadIdx.x;
  int head = ch >> 7;
  float c = 0.f, P = 1.f;
  size_t t0 = (size_t)b * SEQ + (size_t)seg * SEGLEN;
  for (int tt = 0; tt < SEGLEN; ++tt) {
    size_t bt = t0 + tt;
    float f = fg[bt * NHEADS + head];
    float iv = (float)gi[bt * HIDDEN + ch];
    float tv = (float)gt[bt * HIDDEN + ch];
    c = fmaf(f, c, iv * tv);
    P *= f;
  }
  size_t o = ((size_t)b * NSEG + seg) * HIDDEN + ch;
  cend[o] = c;
  pseg[o] = P;
}

__global__ void scan_pass2(const float* __restrict__ cend, const float* __restrict__ pseg,
                           float* __restrict__ cin) {
  int idx = blockIdx.x * 256 + threadIdx.x;  // 4096
  int b = idx >> 11, ch = idx & 2047;
  float C = 0.f;
  for (int s = 0; s < NSEG; ++s) {
    size_t o = ((size_t)b * NSEG + s) * HIDDEN + ch;
    cin[o] = C;
    C = cend[o] + pseg[o] * C;
  }
}

__global__ void scan_pass3(const float* __restrict__ fg, const bf16_t* __restrict__ gi,
                           const bf16_t* __restrict__ gt, const bf16_t* __restrict__ go,
                           const float* __restrict__ cin, bf16_t* __restrict__ h) {
  int bx = blockIdx.x;
  int chblk = bx & 7, seg = (bx >> 3) & 63, b = bx >> 9;
  int ch = chblk * 256 + threadIdx.x;
  int head = ch >> 7;
  float c = cin[((size_t)b * NSEG + seg) * HIDDEN + ch];
  size_t t0 = (size_t)b * SEQ + (size_t)seg * SEGLEN;
  for (int tt = 0; tt < SEGLEN; ++tt) {
    size_t bt = t0 + tt;
    float f = fg[bt * NHEADS + head];
    float iv = (float)gi[bt * HIDDEN + ch];
    float tv = (float)gt[bt * HIDDEN + ch];
    c = fmaf(f, c, iv * tv);
    float hv = (float)go[bt * HIDDEN + ch] * tanhf(c);
    h[bt * HIDDEN + ch] = (bf16_t)hv;
  }
}

extern "C" void kernel_launch(void* const* d_in, const int* in_sizes, int n_in,
                              void* d_out, int out_size, void* d_ws, size_t ws_size,
                              hipStream_t stream) {
  const float* x  = (const float*)d_in[0];
  const float* Wg = (const float*)d_in[1];
  const float* bg = (const float*)d_in[2];
  const float* Wo = (const float*)d_in[3];
  const float* bo = (const float*)d_in[4];
  float* out = (float*)d_out;

  char* ws = (char*)d_ws;
  size_t off = 0;
  auto alloc = [&](size_t bytes) -> void* {
    void* p = ws + off;
    off += (bytes + 255) & ~(size_t)255;
    return p;
  };
  bf16_t* xb   = (bf16_t*)alloc((size_t)BT * DIM * 2);
  bf16_t* wgb  = (bf16_t*)alloc((size_t)N_GATE * DIM * 2);
  bf16_t* wob  = (bf16_t*)alloc((size_t)DIM * HIDDEN * 2);
  float*  fg   = (float*)alloc((size_t)BT * NHEADS * 4);
  bf16_t* gi   = (bf16_t*)alloc((size_t)BT * HIDDEN * 2);
  bf16_t* gt   = (bf16_t*)alloc((size_t)BT * HIDDEN * 2);
  bf16_t* go   = (bf16_t*)alloc((size_t)BT * HIDDEN * 2);
  bf16_t* hbuf = (bf16_t*)alloc((size_t)BT * HIDDEN * 2);
  float*  cend = (float*)alloc((size_t)BATCH * NSEG * HIDDEN * 4);
  float*  pseg = (float*)alloc((size_t)BATCH * NSEG * HIDDEN * 4);
  float*  cin  = (float*)alloc((size_t)BATCH * NSEG * HIDDEN * 4);
  (void)ws_size; (void)in_sizes; (void)n_in; (void)out_size;

  // prep converts
  {
    int n4 = BT * DIM / 4;
    cvt_f32_bf16<<<(n4 + 255) / 256, 256, 0, stream>>>(x, xb, n4);
  }
  {
    int n4 = N_GATE * DIM / 4;
    cvt_f32_bf16<<<(n4 + 255) / 256, 256, 0, stream>>>(Wg + (size_t)NHEADS * DIM, wgb, n4);
  }
  {
    int n4 = DIM * HIDDEN / 4;
    cvt_f32_bf16<<<(n4 + 255) / 256, 256, 0, stream>>>(Wo, wob, n4);
  }

  // f gate in fp32
  fgate_kernel<<<(BT * NHEADS) / 256, 256, 0, stream>>>(x, Wg, bg, fg);

  // gates GEMM: M=8192, N=6144, K=2048 -> 32x24 = 768 tiles
  gemm256<0><<<768, 512, 0, stream>>>(xb, wgb, bg + NHEADS, gi, gt, go, nullptr, 24);

  // segmented scan
  scan_pass1<<<BATCH * NSEG * (HIDDEN / 256), 256, 0, stream>>>(fg, gi, gt, cend, pseg);
  scan_pass2<<<BATCH * HIDDEN / 256, 256, 0, stream>>>(cend, pseg, cin);
  scan_pass3<<<BATCH * NSEG * (HIDDEN / 256), 256, 0, stream>>>(fg, gi, gt, go, cin, hbuf);

  // output GEMM: M=8192, N=2048, K=2048 -> 32x8 = 256 tiles
  gemm256<1><<<256, 512, 0, stream>>>(hbuf, wob, bo, nullptr, nullptr, nullptr, out, 8);
}